// Round 4
// baseline (6583.486 us; speedup 1.0000x reference)
//
#include <hip/hip_runtime.h>
#include <math.h>

// VectorCapsules fused v4 — one 1024-thread workgroup per batch element.
// vs v3: __launch_bounds__(1024,4) -> VGPR cap 128 (v3's bare (1024) made the
// compiler target 64 VGPR and spill 2.8GB of scratch traffic); phase 2 split
// into two c-passes so only 2 pc[14] arrays are live at once (28 regs not 56).
// u[] stays in registers; routing reuses phase-2 ownership.

#define NTH    1024
#define NW     16        // waves per block
#define IC     6272      // 32*14*14 capsules
#define NCLS   5

__global__ __launch_bounds__(NTH, 4)
void caps_fused(const float* __restrict__ inp,
                const float* __restrict__ W1,
                const float* __restrict__ b1,
                const float* __restrict__ Wp,
                const float* __restrict__ bp,
                const float* __restrict__ capsW,
                const float* __restrict__ broute,
                float* __restrict__ out)
{
    extern __shared__ float lds[];
    float* s_in  = lds;              // 3481
    float* s_W1  = s_in + 3481;      // 800
    float* s_b1  = s_W1 + 800;       // 32
    float* s_bp  = s_b1 + 32;        // 448
    float* s_xs  = s_bp + 448;       // 6272 : xs[c][hw], 32 x 196
    float* s_wp  = s_xs + 6272;      // 7168 : per-gi Wp slices, [slice][c][i] = [16][32][14]
    float* s_red = s_wp + 7168;      // 80 (16 waves x 5)
    float* s_v   = s_red + 80;       // 8 (5 used)

    const int b    = blockIdx.x;
    const int tid  = threadIdx.x;
    const int lane = tid & 63;
    const int wv   = tid >> 6;

    // ---------------- Phase 0: stage ----------------
    const float* inb = inp + (size_t)b * (59 * 59);
    for (int i = tid; i < 59 * 59; i += NTH) s_in[i] = inb[i];
    for (int i = tid; i < 800;     i += NTH) s_W1[i] = W1[i];
    if (tid < 32) s_b1[tid] = b1[tid];
    if (tid < 448) s_bp[tid] = bp[tid];
    __syncthreads();

    // ---------------- Phase 1: conv (only ::2,::2 outputs => stride 4) ----
    for (int n = tid; n < IC; n += NTH) {
        const int c  = n / 196;
        const int hw = n - c * 196;
        const int h  = hw / 14;
        const int w  = hw - h * 14;
        const float* ip = s_in + (4 * h) * 59 + 4 * w;
        const float* wk = s_W1 + c * 25;
        float acc = s_b1[c];
        #pragma unroll
        for (int kh = 0; kh < 5; ++kh)
            #pragma unroll
            for (int kw = 0; kw < 5; ++kw)
                acc = fmaf(ip[kh * 59 + kw], wk[kh * 5 + kw], acc);
        s_xs[n] = fmaxf(acc, 0.0f);
    }

    // ---------------- Phase 2: pc -> squash -> u (registers) ----------------
    // wave wv handles g = wv + gi*16, gi in {0,1}; lane covers hw in 4 rounds.
    // Two c-passes per gi: rounds {0,1} then {2,3} -> only 28 pc regs live.
    float u[2][4][NCLS];   // per-thread capsule outputs (static indexing only)

    // EMIT: squash + caps matvec into u registers (GI, R compile-time)
    #define EMIT(PC, GI, R)                                                 \
    {                                                                       \
        const int hw = (R) * 64 + lane;                                     \
        if (hw < 196) {                                                     \
            const int n = ((wv) + (GI) * 16) * 196 + hw;                    \
            float sq = 0.f;                                                 \
            _Pragma("unroll")                                               \
            for (int i = 0; i < 14; ++i) sq = fmaf(PC[i], PC[i], sq);       \
            const float scale = sqrtf(sq) / (1.0f + sq);                    \
            float uo[NCLS] = {0.f, 0.f, 0.f, 0.f, 0.f};                     \
            const float* cw = capsW + (size_t)n * 70;                       \
            _Pragma("unroll")                                               \
            for (int i = 0; i < 14; ++i) {                                  \
                const float p = PC[i] * scale;                              \
                _Pragma("unroll")                                           \
                for (int o = 0; o < NCLS; ++o)                              \
                    uo[o] = fmaf(p, cw[i * 5 + o], uo[o]);                  \
            }                                                               \
            _Pragma("unroll")                                               \
            for (int o = 0; o < NCLS; ++o) u[GI][R][o] = uo[o];             \
        } else {                                                            \
            _Pragma("unroll")                                               \
            for (int o = 0; o < NCLS; ++o) u[GI][R][o] = 0.f;               \
        }                                                                   \
    }

    #pragma unroll
    for (int gi = 0; gi < 2; ++gi) {
        // stage Wp slices for this gi: s_wp[slice][c][i] = Wp[(slice+gi*16)*448 + i*32 + c]
        __syncthreads();   // xs writers done (gi=0) / prior s_wp readers done (gi=1)
        for (int idx = tid; idx < 16 * 448; idx += NTH) {
            const int c     = idx & 31;          // fastest -> coalesced global read
            const int i     = (idx >> 5) % 14;
            const int slice = idx / 448;
            s_wp[slice * 448 + c * 14 + i] = Wp[(size_t)(slice + gi * 16) * 448 + i * 32 + c];
        }
        __syncthreads();

        const int g = wv + gi * 16;
        const float* wpb = s_wp + wv * 448;

        // ---- pass A: rounds 0,1 ----
        {
            float pcA[14], pcB[14];
            #pragma unroll
            for (int i = 0; i < 14; ++i) {
                const float bias = s_bp[g * 14 + i];
                pcA[i] = bias; pcB[i] = bias;
            }
            for (int c = 0; c < 32; ++c) {
                const float* xc = s_xs + c * 196;
                const float xA = xc[lane];
                const float xB = xc[64 + lane];
                const float* wc = wpb + c * 14;
                #pragma unroll
                for (int i = 0; i < 14; ++i) {
                    const float w = wc[i];           // wave-uniform LDS broadcast
                    pcA[i] = fmaf(w, xA, pcA[i]);
                    pcB[i] = fmaf(w, xB, pcB[i]);
                }
            }
            EMIT(pcA, gi, 0) EMIT(pcB, gi, 1)
        }
        // ---- pass B: rounds 2,3 ----
        {
            float pcA[14], pcB[14];
            #pragma unroll
            for (int i = 0; i < 14; ++i) {
                const float bias = s_bp[g * 14 + i];
                pcA[i] = bias; pcB[i] = bias;
            }
            for (int c = 0; c < 32; ++c) {
                const float* xc = s_xs + c * 196;
                const float xA = xc[128 + lane];
                const float xB = xc[192 + (lane & 3)];   // only lanes<4 real
                const float* wc = wpb + c * 14;
                #pragma unroll
                for (int i = 0; i < 14; ++i) {
                    const float w = wc[i];
                    pcA[i] = fmaf(w, xA, pcA[i]);
                    pcB[i] = fmaf(w, xB, pcB[i]);
                }
            }
            EMIT(pcA, gi, 2) EMIT(pcB, gi, 3)
        }
    }
    #undef EMIT
    __syncthreads();

    // ---------------- Phase 3: routing (initial + 3 iters), u in regs ------
    float V[NCLS] = {0.f, 0.f, 0.f, 0.f, 0.f};
    for (int it = 0; it < 4; ++it) {
        float sacc[NCLS] = {0.f, 0.f, 0.f, 0.f, 0.f};
        #pragma unroll
        for (int gi = 0; gi < 2; ++gi) {
            const int g = wv + gi * 16;
            #pragma unroll
            for (int r = 0; r < 4; ++r) {
                const int hw = r * 64 + lane;
                if (hw < 196) {
                    const int n = g * 196 + hw;
                    const float* br = broute + (size_t)n * 5;
                    float l[NCLS];
                    #pragma unroll
                    for (int o = 0; o < NCLS; ++o)
                        l[o] = fmaf(u[gi][r][o], V[o], br[o]);
                    const float m = fmaxf(fmaxf(fmaxf(l[0], l[1]), fmaxf(l[2], l[3])), l[4]);
                    float e[NCLS], es = 0.f;
                    #pragma unroll
                    for (int o = 0; o < NCLS; ++o) { e[o] = __expf(l[o] - m); es += e[o]; }
                    const float inv = 1.0f / es;
                    #pragma unroll
                    for (int o = 0; o < NCLS; ++o)
                        sacc[o] = fmaf(u[gi][r][o], e[o] * inv, sacc[o]);
                }
            }
        }
        // wave reduce then cross-wave via LDS
        #pragma unroll
        for (int off = 32; off > 0; off >>= 1)
            #pragma unroll
            for (int o = 0; o < NCLS; ++o)
                sacc[o] += __shfl_down(sacc[o], off);
        if (lane == 0) {
            #pragma unroll
            for (int o = 0; o < NCLS; ++o) s_red[wv * 5 + o] = sacc[o];
        }
        __syncthreads();
        if (tid < NCLS) {
            float s = 0.f;
            for (int w2 = 0; w2 < NW; ++w2) s += s_red[w2 * 5 + tid];
            s_v[tid] = s * fabsf(s) / (1.0f + s * s);   // squash, OUT_DIM=1
        }
        __syncthreads();
        #pragma unroll
        for (int o = 0; o < NCLS; ++o) V[o] += s_v[o];
    }

    if (tid < NCLS) out[b * NCLS + tid] = fabsf(s_v[tid]);
}

extern "C" void kernel_launch(void* const* d_in, const int* in_sizes, int n_in,
                              void* d_out, int out_size, void* d_ws, size_t ws_size,
                              hipStream_t stream)
{
    const float* inp   = (const float*)d_in[0];
    // d_in[1] = r (python scalar, unused by reference)
    const float* W1    = (const float*)d_in[2];
    const float* b1    = (const float*)d_in[3];
    const float* Wp    = (const float*)d_in[4];
    const float* bp    = (const float*)d_in[5];
    const float* capsW = (const float*)d_in[6];
    const float* brt   = (const float*)d_in[7];
    float* out = (float*)d_out;

    const int B = in_sizes[0] / (59 * 59);   // 1024
    const size_t lds_bytes = (size_t)(3481 + 800 + 32 + 448 + 6272 + 7168 + 80 + 8) * sizeof(float);
    (void)hipFuncSetAttribute((const void*)caps_fused,
                              hipFuncAttributeMaxDynamicSharedMemorySize,
                              (int)lds_bytes);
    caps_fused<<<B, NTH, lds_bytes, stream>>>(inp, W1, b1, Wp, bp, capsW, brt, out);
}

// Round 5
// 686.868 us; speedup vs baseline: 9.5848x; 9.5848x over previous
//
#include <hip/hip_runtime.h>
#include <math.h>

// VectorCapsules fused v5 — back to the proven v2 shell (512 thr, u in LDS,
// 1 block/CU, no spill) with phase-2 rebuilt:
//  - Wp/bp reads scalarized via readfirstlane -> s_load (SMEM), zero VMEM in
//    the einsum inner loop, FMAs are v*s+v.
//  - xs stored TRANSPOSED + XOR-swizzled in LDS: per round each thread loads
//    its 32 x values as 8 conflict-free ds_read_b128 (was 32 stride-196 b32).
//  - i-outer / c-inner so the 32 scalar w loads per i are contiguous (merge
//    into wide s_loads).

#define NTH    512
#define NWAVES 8
#define IC     6272      // 32*14*14 capsules
#define NCLS   5

__global__ __launch_bounds__(NTH, 1)
void caps_fused(const float* __restrict__ inp,
                const float* __restrict__ W1,
                const float* __restrict__ b1,
                const float* __restrict__ Wp,
                const float* __restrict__ bp,
                const float* __restrict__ capsW,
                const float* __restrict__ broute,
                float* __restrict__ out)
{
    extern __shared__ float lds[];
    float* s_xs  = lds;            // 6272 : xs TRANSPOSED [hw][c'], c' swizzled
    float* s_W1  = s_xs + 6272;    // 800
    float* s_b1  = s_W1 + 800;     // 32
    float* s_red = s_b1 + 32;      // 40 (8 waves x 5)
    float* s_v   = s_red + 40;     // 8 (5 used)
    float* s_u   = s_v + 8;        // 31360 : u[n][5]  (aliases s_in[3481])
    float* s_in  = s_u;            // 3481 during phases 0/1 only

    const int b    = blockIdx.x;
    const int tid  = threadIdx.x;
    const int lane = tid & 63;
    const int wv   = tid >> 6;
    const int wvs  = __builtin_amdgcn_readfirstlane(wv);   // provably uniform

    // ---------------- Phase 0: stage ----------------
    const float* inb = inp + (size_t)b * (59 * 59);
    for (int i = tid; i < 59 * 59; i += NTH) s_in[i] = inb[i];
    for (int i = tid; i < 800;     i += NTH) s_W1[i] = W1[i];
    if (tid < 32) s_b1[tid] = b1[tid];
    __syncthreads();

    // ---------------- Phase 1: conv (::2,::2 kept => stride 4) ----------
    // write transposed+swizzled: s_xs[hw*32 + 4*((c>>2)^(hw&7)) + (c&3)]
    for (int n = tid; n < IC; n += NTH) {
        const int c  = n / 196;
        const int hw = n - c * 196;
        const int h  = hw / 14;
        const int w  = hw - h * 14;
        const float* ip = s_in + (4 * h) * 59 + 4 * w;
        const float* wk = s_W1 + c * 25;
        float acc = s_b1[c];
        #pragma unroll
        for (int kh = 0; kh < 5; ++kh)
            #pragma unroll
            for (int kw = 0; kw < 5; ++kw)
                acc = fmaf(ip[kh * 59 + kw], wk[kh * 5 + kw], acc);
        const int col = 4 * ((c >> 2) ^ (hw & 7)) + (c & 3);
        s_xs[hw * 32 + col] = fmaxf(acc, 0.0f);
    }
    __syncthreads();
    // s_in region is dead from here; s_u may overwrite it.

    // ---------------- Phase 2: pc -> squash -> u (LDS) ----------------
    // wave wv handles g = wvs + gi*8, gi in 0..3; two 2-round passes per g.
    const float4* xs4 = (const float4*)s_xs;

    #define EMIT(PC, HW)                                                    \
    {                                                                       \
        if ((HW) < 196) {                                                   \
            const int n = g * 196 + (HW);                                   \
            float sq = 0.f;                                                 \
            _Pragma("unroll")                                               \
            for (int i = 0; i < 14; ++i) sq = fmaf(PC[i], PC[i], sq);       \
            const float scale = sqrtf(sq) / (1.0f + sq);                    \
            float uo[NCLS] = {0.f, 0.f, 0.f, 0.f, 0.f};                     \
            const float* cw = capsW + (size_t)n * 70;                       \
            _Pragma("unroll")                                               \
            for (int i = 0; i < 14; ++i) {                                  \
                const float p = PC[i] * scale;                              \
                _Pragma("unroll")                                           \
                for (int o = 0; o < NCLS; ++o)                              \
                    uo[o] = fmaf(p, cw[i * 5 + o], uo[o]);                  \
            }                                                               \
            _Pragma("unroll")                                               \
            for (int o = 0; o < NCLS; ++o) s_u[n * 5 + o] = uo[o];          \
        }                                                                   \
    }

    for (int gi = 0; gi < 4; ++gi) {
        const int g = wvs + gi * 8;                 // scalar (SGPR)
        const float* wpg = Wp + g * 448;            // uniform -> s_load
        const float* bpg = bp + g * 14;             // uniform -> s_load

        #pragma unroll
        for (int p = 0; p < 2; ++p) {
            const int hwA = p * 128 + lane;                       // rounds 2p
            const int hwB = p ? (192 + (lane & 3)) : (64 + lane); // 2p+1
            float xA[32], xB[32];
            #pragma unroll
            for (int j = 0; j < 8; ++j) {
                const float4 a  = xs4[hwA * 8 + (j ^ (hwA & 7))];
                const float4 bb = xs4[hwB * 8 + (j ^ (hwB & 7))];
                xA[4*j+0] = a.x;  xA[4*j+1] = a.y;  xA[4*j+2] = a.z;  xA[4*j+3] = a.w;
                xB[4*j+0] = bb.x; xB[4*j+1] = bb.y; xB[4*j+2] = bb.z; xB[4*j+3] = bb.w;
            }

            float pcA[14], pcB[14];
            #pragma unroll
            for (int i = 0; i < 14; ++i) {
                const float bias = bpg[i];          // s_load
                pcA[i] = bias; pcB[i] = bias;
            }
            #pragma unroll
            for (int i = 0; i < 14; ++i) {
                const float* wr = wpg + i * 32;     // 32 contiguous scalars
                #pragma unroll
                for (int c = 0; c < 32; ++c) {
                    const float w = wr[c];          // s_load (merged wide)
                    pcA[i] = fmaf(w, xA[c], pcA[i]);
                    pcB[i] = fmaf(w, xB[c], pcB[i]);
                }
            }
            EMIT(pcA, hwA)
            EMIT(pcB, hwB)
        }
    }
    #undef EMIT
    __syncthreads();

    // ---------------- Phase 3: routing (initial + 3 iters) ----------------
    float V[NCLS] = {0.f, 0.f, 0.f, 0.f, 0.f};
    for (int it = 0; it < 4; ++it) {
        float sacc[NCLS] = {0.f, 0.f, 0.f, 0.f, 0.f};
        for (int n = tid; n < IC; n += NTH) {
            const float* br = broute + (size_t)n * 5;
            float uu[NCLS], l[NCLS];
            #pragma unroll
            for (int o = 0; o < NCLS; ++o) {
                uu[o] = s_u[n * 5 + o];
                l[o]  = fmaf(uu[o], V[o], br[o]);
            }
            const float m = fmaxf(fmaxf(fmaxf(l[0], l[1]), fmaxf(l[2], l[3])), l[4]);
            float e[NCLS], es = 0.f;
            #pragma unroll
            for (int o = 0; o < NCLS; ++o) { e[o] = __expf(l[o] - m); es += e[o]; }
            const float inv = 1.0f / es;
            #pragma unroll
            for (int o = 0; o < NCLS; ++o)
                sacc[o] = fmaf(uu[o], e[o] * inv, sacc[o]);
        }
        #pragma unroll
        for (int off = 32; off > 0; off >>= 1)
            #pragma unroll
            for (int o = 0; o < NCLS; ++o)
                sacc[o] += __shfl_down(sacc[o], off);
        if (lane == 0) {
            #pragma unroll
            for (int o = 0; o < NCLS; ++o) s_red[wv * 5 + o] = sacc[o];
        }
        __syncthreads();
        if (tid == 0) {
            #pragma unroll
            for (int o = 0; o < NCLS; ++o) {
                float s = 0.f;
                for (int w2 = 0; w2 < NWAVES; ++w2) s += s_red[w2 * 5 + o];
                s_v[o] = s * fabsf(s) / (1.0f + s * s);   // squash, OUT_DIM=1
            }
        }
        __syncthreads();
        #pragma unroll
        for (int o = 0; o < NCLS; ++o) V[o] += s_v[o];
    }

    if (tid < NCLS) out[b * NCLS + tid] = fabsf(s_v[tid]);
}

extern "C" void kernel_launch(void* const* d_in, const int* in_sizes, int n_in,
                              void* d_out, int out_size, void* d_ws, size_t ws_size,
                              hipStream_t stream)
{
    const float* inp   = (const float*)d_in[0];
    // d_in[1] = r (python scalar, unused by reference)
    const float* W1    = (const float*)d_in[2];
    const float* b1    = (const float*)d_in[3];
    const float* Wp    = (const float*)d_in[4];
    const float* bp    = (const float*)d_in[5];
    const float* capsW = (const float*)d_in[6];
    const float* brt   = (const float*)d_in[7];
    float* out = (float*)d_out;

    const int B = in_sizes[0] / (59 * 59);   // 1024
    const size_t lds_bytes = (size_t)(6272 + 800 + 32 + 40 + 8 + 31360) * sizeof(float);
    (void)hipFuncSetAttribute((const void*)caps_fused,
                              hipFuncAttributeMaxDynamicSharedMemorySize,
                              (int)lds_bytes);
    caps_fused<<<B, NTH, lds_bytes, stream>>>(inp, W1, b1, Wp, bp, capsW, brt, out);
}